// Round 8
// baseline (547.502 us; speedup 1.0000x reference)
//
#include <hip/hip_runtime.h>
#include <hip/hip_fp16.h>

#define HID 64

typedef _Float16 half8 __attribute__((ext_vector_type(8)));
typedef _Float16 half4 __attribute__((ext_vector_type(4)));

// ---------------- degree count + per-edge rank (atomic return value) ----------
__global__ void k_count_rank(const int* __restrict__ dst, int* __restrict__ deg,
                             int* __restrict__ rank, int E) {
  int e = blockIdx.x * blockDim.x + threadIdx.x;
  if (e < E) rank[e] = atomicAdd(&deg[dst[e]], 1);
}

// ---------------- exclusive scan of deg -> rowoff (+ fused dis=rsqrt(deg+1)) ----
__global__ void k_scan1(const int* __restrict__ deg, int* __restrict__ scanout,
                        int* __restrict__ blocksums, float* __restrict__ dis, int n) {
  __shared__ int sdata[256];
  int tid = threadIdx.x;
  int base = blockIdx.x * 1024 + tid * 4;
  int v0 = 0, v1 = 0, v2 = 0, v3 = 0;
  if (base + 0 < n) v0 = deg[base + 0];
  if (base + 1 < n) v1 = deg[base + 1];
  if (base + 2 < n) v2 = deg[base + 2];
  if (base + 3 < n) v3 = deg[base + 3];
  if (base + 0 < n) dis[base + 0] = rsqrtf((float)v0 + 1.0f);
  if (base + 1 < n) dis[base + 1] = rsqrtf((float)v1 + 1.0f);
  if (base + 2 < n) dis[base + 2] = rsqrtf((float)v2 + 1.0f);
  if (base + 3 < n) dis[base + 3] = rsqrtf((float)v3 + 1.0f);
  int tsum = v0 + v1 + v2 + v3;
  sdata[tid] = tsum;
  __syncthreads();
  for (int off = 1; off < 256; off <<= 1) {
    int t = (tid >= off) ? sdata[tid - off] : 0;
    __syncthreads();
    sdata[tid] += t;
    __syncthreads();
  }
  int excl = sdata[tid] - tsum;
  if (base + 0 < n) scanout[base + 0] = excl;
  if (base + 1 < n) scanout[base + 1] = excl + v0;
  if (base + 2 < n) scanout[base + 2] = excl + v0 + v1;
  if (base + 3 < n) scanout[base + 3] = excl + v0 + v1 + v2;
  if (tid == 255) blocksums[blockIdx.x] = sdata[255];
}

__global__ void k_scan2(int* blocksums, int nb) {
  __shared__ int s[128];
  int tid = threadIdx.x;
  int v = (tid < nb) ? blocksums[tid] : 0;
  s[tid] = v;
  __syncthreads();
  for (int off = 1; off < 128; off <<= 1) {
    int t = (tid >= off) ? s[tid - off] : 0;
    __syncthreads();
    s[tid] += t;
    __syncthreads();
  }
  if (tid < nb) blocksums[tid] = s[tid] - v;
}

__global__ void k_scan3(const int* __restrict__ scanout,
                        const int* __restrict__ blocksums, int* __restrict__ rowoff,
                        int n) {
  int i = blockIdx.x * blockDim.x + threadIdx.x;
  if (i < n) rowoff[i] = scanout[i] + blocksums[i >> 10];
}

// ---------------- deterministic scatter (no atomics) ----------------
__global__ void k_scatter_det(const int* __restrict__ src, const int* __restrict__ dst,
                              const int* __restrict__ rowoff,
                              const int* __restrict__ rank,
                              int* __restrict__ csr_src, int E) {
  int e = blockIdx.x * blockDim.x + threadIdx.x;
  if (e >= E) return;
  int pos = rowoff[dst[e]] + rank[e];
  csr_src[pos] = src[e];
}

// ---------------- node linear (fp32 in, f16 out, pre-scaled by dis[r]) --------
// writes rows [0,n); row n is the zero sentinel.
__global__ __launch_bounds__(256) void k_lin_f32in(const float* __restrict__ X,
                                                   const float* __restrict__ W,
                                                   const float* __restrict__ dis,
                                                   __half* __restrict__ Y, int n) {
  int r = blockIdx.x * blockDim.x + threadIdx.x;
  if (r > n) return;
  float4* yr = (float4*)(Y + (long)r * HID);
  if (r == n) {  // sentinel zero row
    float4 zz = {0.f, 0.f, 0.f, 0.f};
#pragma unroll
    for (int g = 0; g < 8; ++g) yr[g] = zz;
    return;
  }
  float z[HID];
#pragma unroll
  for (int c = 0; c < HID; ++c) z[c] = 0.f;
  const float* xr = X + (long)r * 128;
  for (int kc = 0; kc < 8; ++kc) {
    const float4* xp = (const float4*)(xr + kc * 16);
    float4 a0 = xp[0], a1 = xp[1], a2 = xp[2], a3 = xp[3];
    float ev[16] = {a0.x, a0.y, a0.z, a0.w, a1.x, a1.y, a1.z, a1.w,
                    a2.x, a2.y, a2.z, a2.w, a3.x, a3.y, a3.z, a3.w};
#pragma unroll
    for (int k = 0; k < 16; ++k) {
      const float* wr = W + (kc * 16 + k) * HID;
      float ek = ev[k];
#pragma unroll
      for (int c = 0; c < HID; ++c) z[c] = fmaf(ek, wr[c], z[c]);
    }
  }
  float ddr = dis[r];
  union { __half h[8]; float4 f; } u;
#pragma unroll
  for (int g = 0; g < 8; ++g) {
#pragma unroll
    for (int j = 0; j < 8; ++j) u.h[j] = __float2half(z[g * 8 + j] * ddr);
    yr[g] = u.f;
  }
}

// ---------------- node linear 64->64 (f16 in, f16 out, pre-scaled by dis[r]) --
__global__ __launch_bounds__(256) void k_lin64(const __half* __restrict__ X,
                                               const float* __restrict__ W,
                                               const float* __restrict__ dis,
                                               __half* __restrict__ Y, int n) {
  int r = blockIdx.x * blockDim.x + threadIdx.x;
  if (r > n) return;
  float4* yr = (float4*)(Y + (long)r * HID);
  if (r == n) {  // sentinel zero row
    float4 zz = {0.f, 0.f, 0.f, 0.f};
#pragma unroll
    for (int g = 0; g < 8; ++g) yr[g] = zz;
    return;
  }
  float z[HID];
#pragma unroll
  for (int c = 0; c < HID; ++c) z[c] = 0.f;
  const half8* xr = (const half8*)(X + (long)r * HID);
  for (int kc = 0; kc < 4; ++kc) {
    half8 a0 = xr[kc * 2], a1 = xr[kc * 2 + 1];
    float ev[16];
#pragma unroll
    for (int j = 0; j < 8; ++j) { ev[j] = (float)a0[j]; ev[8 + j] = (float)a1[j]; }
#pragma unroll
    for (int k = 0; k < 16; ++k) {
      const float* wr = W + (kc * 16 + k) * HID;
      float ek = ev[k];
#pragma unroll
      for (int c = 0; c < HID; ++c) z[c] = fmaf(ek, wr[c], z[c]);
    }
  }
  float ddr = dis[r];
  union { __half h[8]; float4 f; } u;
#pragma unroll
  for (int g = 0; g < 8; ++g) {
#pragma unroll
    for (int j = 0; j < 8; ++j) u.h[j] = __float2half(z[g * 8 + j] * ddr);
    yr[g] = u.f;
  }
}

// ---------------- U/V linear: UV[r] = [ h[r]@Wc1a + bc1 | h[r]@Wc1b ] ---------
__global__ __launch_bounds__(256) void k_lin_uv(const __half* __restrict__ X,
                                                const float* __restrict__ Wc1,
                                                const float* __restrict__ bc1,
                                                __half* __restrict__ UV, int n) {
  int r = blockIdx.x * blockDim.x + threadIdx.x;
  if (r >= n) return;
  const half8* xr = (const half8*)(X + (long)r * HID);
  half8 xv[8];
#pragma unroll
  for (int g = 0; g < 8; ++g) xv[g] = xr[g];

  for (int halfsel = 0; halfsel < 2; ++halfsel) {
    const float* W = Wc1 + halfsel * HID * HID;
    float z[HID];
    if (halfsel == 0) {
#pragma unroll
      for (int c = 0; c < HID; ++c) z[c] = bc1[c];
    } else {
#pragma unroll
      for (int c = 0; c < HID; ++c) z[c] = 0.f;
    }
    for (int kc = 0; kc < 4; ++kc) {
      half8 a0 = xv[kc * 2], a1 = xv[kc * 2 + 1];
      float ev[16];
#pragma unroll
      for (int j = 0; j < 8; ++j) { ev[j] = (float)a0[j]; ev[8 + j] = (float)a1[j]; }
#pragma unroll
      for (int k = 0; k < 16; ++k) {
        const float* wr = W + (kc * 16 + k) * HID;
        float ek = ev[k];
#pragma unroll
        for (int c = 0; c < HID; ++c) z[c] = fmaf(ek, wr[c], z[c]);
      }
    }
    union { __half h[8]; float4 f; } u;
    float4* yr = (float4*)(UV + (long)r * 128 + halfsel * HID);
#pragma unroll
    for (int g = 0; g < 8; ++g) {
#pragma unroll
      for (int j = 0; j < 8; ++j) u.h[j] = __float2half(z[g * 8 + j]);
      yr[g] = u.f;
    }
  }
}

// ---------------- CSR aggregation: A = dd * (Yh[node] + sum Yh[s]) + b --------
// Yh rows pre-scaled by dis[s]; row n is a zero sentinel for tail slots.
__global__ __launch_bounds__(256) void k_agg_csr(
    const __half* __restrict__ Yh, const float* __restrict__ dis,
    const int* __restrict__ rowoff, const int* __restrict__ csr_src,
    const float* __restrict__ b, __half* __restrict__ A, int n, int E, int relu) {
  int node = blockIdx.x * 4 + (threadIdx.x >> 6);
  if (node >= n) return;
  int L = threadIdx.x & 63;
  int sub = L >> 4;   // quarter id
  int cq = L & 15;    // channel quad
  const half4* Y4 = (const half4*)Yh;
  float dd = dis[node];
  int i0 = rowoff[node];
  int end = (node == n - 1) ? E : rowoff[node + 1];

  float z[4][4] = {{0.f}};
  if (sub == 0) {  // self term (already scaled by dis[node])
    half4 hv = Y4[(long)node * 16 + cq];
#pragma unroll
    for (int j = 0; j < 4; ++j) z[0][j] = (float)hv[j];
  }

  int last = end - 1;
  for (int base = i0; base < end; base += 16) {
    int sidx[4];
#pragma unroll
    for (int slot = 0; slot < 4; ++slot) {
      int idx = base + slot * 4 + sub;
      int sl = csr_src[min(idx, last)];
      sidx[slot] = (idx < end) ? sl : n;  // sentinel -> zero row
    }
#pragma unroll
    for (int slot = 0; slot < 4; ++slot) {
      half4 hv = Y4[(long)sidx[slot] * 16 + cq];
#pragma unroll
      for (int j = 0; j < 4; ++j) z[slot][j] += (float)hv[j];
    }
  }

  float a[4];
#pragma unroll
  for (int j = 0; j < 4; ++j) {
    a[j] = (z[0][j] + z[1][j]) + (z[2][j] + z[3][j]);
    a[j] += __shfl_xor(a[j], 16, 64);
    a[j] += __shfl_xor(a[j], 32, 64);
  }
  if (sub == 0) {
    float4 bb = ((const float4*)b)[cq];
    float v0 = fmaf(a[0], dd, bb.x), v1 = fmaf(a[1], dd, bb.y);
    float v2 = fmaf(a[2], dd, bb.z), v3 = fmaf(a[3], dd, bb.w);
    if (relu) {
      v0 = fmaxf(v0, 0.f); v1 = fmaxf(v1, 0.f);
      v2 = fmaxf(v2, 0.f); v3 = fmaxf(v3, 0.f);
    }
    half4 o = {(_Float16)v0, (_Float16)v1, (_Float16)v2, (_Float16)v3};
    ((half4*)A)[(long)node * 16 + cq] = o;
  }
}

// ---------------- edge MLP: out_e = relu(U[src]+V[dst]) @ Wc2 + bc2 ----------
// 16 lanes/edge; 8 slots -> 32 edges, 16 row-gathers in flight per wave iter.
__global__ __launch_bounds__(256) void k_edge_mlp(
    const __half* __restrict__ UV, const int* __restrict__ src,
    const int* __restrict__ dst, const float* __restrict__ Wc2,
    const float* __restrict__ bc2, float* __restrict__ out, int E, int nwaves) {
  int wid = blockIdx.x * 4 + (threadIdx.x >> 6);
  int L = threadIdx.x & 63;
  int sub = L >> 4;   // quarter id
  int cq = L & 15;    // channel quad

  float w0[4], w1[4];
#pragma unroll
  for (int j = 0; j < 4; ++j) {
    int c = cq * 4 + j;
    w0[j] = Wc2[2 * c];
    w1[j] = Wc2[2 * c + 1];
  }
  float ob0 = bc2[0], ob1 = bc2[1];

  const half4* UV4 = (const half4*)UV;  // node r: U = [r*32 .. +15], V = [r*32+16 .. +31]
  int last = E - 1;

  for (long base = (long)wid * 32; base < E; base += (long)nwaves * 32) {
    int se[8], de[8];
#pragma unroll
    for (int slot = 0; slot < 8; ++slot) {
      int e = (int)base + slot * 4 + sub;
      int ec = min(e, last);
      se[slot] = src[ec];
      de[slot] = dst[ec];
    }
    half4 uu[8], vv[8];
#pragma unroll
    for (int slot = 0; slot < 8; ++slot) {
      uu[slot] = UV4[(long)se[slot] * 32 + cq];
      vv[slot] = UV4[(long)de[slot] * 32 + 16 + cq];
    }
#pragma unroll
    for (int slot = 0; slot < 8; ++slot) {
      float o0 = 0.f, o1 = 0.f;
#pragma unroll
      for (int j = 0; j < 4; ++j) {
        float v = fmaxf((float)uu[slot][j] + (float)vv[slot][j], 0.f);
        o0 = fmaf(v, w0[j], o0);
        o1 = fmaf(v, w1[j], o1);
      }
      o0 += __shfl_xor(o0, 1, 64);
      o1 += __shfl_xor(o1, 1, 64);
      o0 += __shfl_xor(o0, 2, 64);
      o1 += __shfl_xor(o1, 2, 64);
      o0 += __shfl_xor(o0, 4, 64);
      o1 += __shfl_xor(o1, 4, 64);
      o0 += __shfl_xor(o0, 8, 64);
      o1 += __shfl_xor(o1, 8, 64);
      int e = (int)base + slot * 4 + sub;
      if (cq == 0 && e < E) {
        float2 o = {o0 + ob0, o1 + ob1};
        *(float2*)(out + 2 * (long)e) = o;
      }
    }
  }
}

// ---------------- launch ----------------
extern "C" void kernel_launch(void* const* d_in, const int* in_sizes, int n_in,
                              void* d_out, int out_size, void* d_ws, size_t ws_size,
                              hipStream_t stream) {
  const float* x   = (const float*)d_in[0];
  const int*   ei  = (const int*)d_in[1];
  const float* W1  = (const float*)d_in[2];
  const float* b1  = (const float*)d_in[3];
  const float* W2  = (const float*)d_in[4];
  const float* b2  = (const float*)d_in[5];
  const float* Wc1 = (const float*)d_in[6];
  const float* bc1 = (const float*)d_in[7];
  const float* Wc2 = (const float*)d_in[8];
  const float* bc2 = (const float*)d_in[9];

  const int N = in_sizes[0] / 128;
  const int E = in_sizes[1] / 2;
  const int* src = ei;
  const int* dst = ei + E;

  // workspace layout
  float* dis    = (float*)d_ws;                    // N f32
  __half* y     = (__half*)(dis + N);              // (N+1)*64 f16 (sentinel row N)
  __half* h     = y + (long)(N + 1) * HID;         // N*64 f16
  __half* UV    = h + (long)N * HID;               // N*128 f16 (interleaved U|V)
  int* degi     = (int*)(UV + (long)N * 128);      // N
  int* scanout  = degi + N;                        // N
  int* rowoff   = scanout + N;                     // N
  int* blocksums= rowoff + N;                      // 128
  int* csr_src  = blocksums + 128;                 // E
  int* rank     = (int*)y;  // E ints <= (N+1)*64 f16 bytes; dead once y written

  const int B = 256;
  int gN  = (N + B - 1) / B;
  int gN1 = (N + 1 + B - 1) / B;  // covers sentinel row
  int gE  = (E + B - 1) / B;
  int nb  = (N + 1023) / 1024;

  // ---- CSR build ----
  hipMemsetAsync(degi, 0, (size_t)N * sizeof(int), stream);
  k_count_rank<<<gE, B, 0, stream>>>(dst, degi, rank, E);
  k_scan1<<<nb, B, 0, stream>>>(degi, scanout, blocksums, dis, N);
  k_scan2<<<1, 128, 0, stream>>>(blocksums, nb);
  k_scan3<<<gN, B, 0, stream>>>(scanout, blocksums, rowoff, N);
  k_scatter_det<<<gE, B, 0, stream>>>(src, dst, rowoff, rank, csr_src, E);

  int gAgg = (N + 3) / 4;

  // ---- layer 1: y = (x@W1)*dis ; h = relu(dd*(y_self+sum y) + b1) ----
  k_lin_f32in<<<gN1, B, 0, stream>>>(x, W1, dis, y, N);
  k_agg_csr<<<gAgg, B, 0, stream>>>(y, dis, rowoff, csr_src, b1, h, N, E, 1);

  // ---- layer 2 ----
  k_lin64<<<gN1, B, 0, stream>>>(h, W2, dis, y, N);
  k_agg_csr<<<gAgg, B, 0, stream>>>(y, dis, rowoff, csr_src, b2, h, N, E, 0);

  // ---- classifier: UV = [h@Wc1a + bc1 | h@Wc1b] ; edge MLP ----
  k_lin_uv<<<gN, B, 0, stream>>>(h, Wc1, bc1, UV, N);
  int cblocks = 2048;
  int nwaves = cblocks * 4;
  k_edge_mlp<<<cblocks, B, 0, stream>>>(UV, src, dst, Wc2, bc2,
                                        (float*)d_out, E, nwaves);
}

// Round 9
// 387.988 us; speedup vs baseline: 1.4111x; 1.4111x over previous
//
#include <hip/hip_runtime.h>
#include <hip/hip_fp16.h>

#define HID 64

typedef _Float16 half8 __attribute__((ext_vector_type(8)));
typedef _Float16 half4 __attribute__((ext_vector_type(4)));
typedef float f32x4 __attribute__((ext_vector_type(4)));

// ---------------- degree count + per-edge rank (atomic return value) ----------
__global__ void k_count_rank(const int* __restrict__ dst, int* __restrict__ deg,
                             int* __restrict__ rank, int E) {
  int e = blockIdx.x * blockDim.x + threadIdx.x;
  if (e < E) rank[e] = atomicAdd(&deg[dst[e]], 1);
}

// ---------------- exclusive scan of deg -> rowoff (+ fused dis=rsqrt(deg+1)) ----
__global__ void k_scan1(const int* __restrict__ deg, int* __restrict__ scanout,
                        int* __restrict__ blocksums, float* __restrict__ dis, int n) {
  __shared__ int sdata[256];
  int tid = threadIdx.x;
  int base = blockIdx.x * 1024 + tid * 4;
  int v0 = 0, v1 = 0, v2 = 0, v3 = 0;
  if (base + 0 < n) v0 = deg[base + 0];
  if (base + 1 < n) v1 = deg[base + 1];
  if (base + 2 < n) v2 = deg[base + 2];
  if (base + 3 < n) v3 = deg[base + 3];
  if (base + 0 < n) dis[base + 0] = rsqrtf((float)v0 + 1.0f);
  if (base + 1 < n) dis[base + 1] = rsqrtf((float)v1 + 1.0f);
  if (base + 2 < n) dis[base + 2] = rsqrtf((float)v2 + 1.0f);
  if (base + 3 < n) dis[base + 3] = rsqrtf((float)v3 + 1.0f);
  int tsum = v0 + v1 + v2 + v3;
  sdata[tid] = tsum;
  __syncthreads();
  for (int off = 1; off < 256; off <<= 1) {
    int t = (tid >= off) ? sdata[tid - off] : 0;
    __syncthreads();
    sdata[tid] += t;
    __syncthreads();
  }
  int excl = sdata[tid] - tsum;
  if (base + 0 < n) scanout[base + 0] = excl;
  if (base + 1 < n) scanout[base + 1] = excl + v0;
  if (base + 2 < n) scanout[base + 2] = excl + v0 + v1;
  if (base + 3 < n) scanout[base + 3] = excl + v0 + v1 + v2;
  if (tid == 255) blocksums[blockIdx.x] = sdata[255];
}

__global__ void k_scan2(int* blocksums, int nb) {
  __shared__ int s[128];
  int tid = threadIdx.x;
  int v = (tid < nb) ? blocksums[tid] : 0;
  s[tid] = v;
  __syncthreads();
  for (int off = 1; off < 128; off <<= 1) {
    int t = (tid >= off) ? s[tid - off] : 0;
    __syncthreads();
    s[tid] += t;
    __syncthreads();
  }
  if (tid < nb) blocksums[tid] = s[tid] - v;
}

__global__ void k_scan3(const int* __restrict__ scanout,
                        const int* __restrict__ blocksums, int* __restrict__ rowoff,
                        int n) {
  int i = blockIdx.x * blockDim.x + threadIdx.x;
  if (i < n) rowoff[i] = scanout[i] + blocksums[i >> 10];
}

// ---------------- deterministic scatter (no atomics) ----------------
__global__ void k_scatter_det(const int* __restrict__ src, const int* __restrict__ dst,
                              const int* __restrict__ rowoff,
                              const int* __restrict__ rank,
                              int* __restrict__ csr_src, int E) {
  int e = blockIdx.x * blockDim.x + threadIdx.x;
  if (e >= E) return;
  int pos = rowoff[dst[e]] + rank[e];
  csr_src[pos] = src[e];
}

// ---------------- fused packing: W1, W2, UV(Wc1) frags + biasUV + y sentinel ---
// B-frag layout (verified r3): frag f=kc*NB+nb; lane L; j:  B[32kc+(L>>4)*8+j][(L&15)+16nb]
__global__ void k_pack_all(const float* __restrict__ W1, const float* __restrict__ W2,
                           const float* __restrict__ Wc1, const float* __restrict__ bc1,
                           __half* __restrict__ packW1, __half* __restrict__ packW2,
                           __half* __restrict__ packUV, float* __restrict__ biasUV,
                           __half* __restrict__ ysent) {
  int b = blockIdx.x, tid = threadIdx.x;
  if (b < 4) {                       // W1: K=128, NOUT=64 -> 16 frags
    int t = b * 256 + tid;
    int f = t >> 6, L = t & 63;
    int kc = f >> 2, nb = f & 3;
    int k = 32 * kc + ((L >> 4) << 3);
    int n = (L & 15) + 16 * nb;
    for (int j = 0; j < 8; ++j)
      packW1[(t << 3) + j] = __float2half(W1[(k + j) * 64 + n]);
  } else if (b < 6) {                // W2: K=64, NOUT=64 -> 8 frags
    int t = (b - 4) * 256 + tid;
    int f = t >> 6, L = t & 63;
    int kc = f >> 2, nb = f & 3;
    int k = 32 * kc + ((L >> 4) << 3);
    int n = (L & 15) + 16 * nb;
    for (int j = 0; j < 8; ++j)
      packW2[(t << 3) + j] = __float2half(W2[(k + j) * 64 + n]);
  } else if (b < 10) {               // UV: K=64, NOUT=128 -> 16 frags
    int t = (b - 6) * 256 + tid;
    int f = t >> 6, L = t & 63;
    int kc = f >> 3, nb = f & 7;
    int k = 32 * kc + ((L >> 4) << 3);
    int n = (L & 15) + 16 * nb;
    for (int j = 0; j < 8; ++j) {
      float w = (n < 64) ? Wc1[(k + j) * 64 + n] : Wc1[(64 + k + j) * 64 + (n - 64)];
      packUV[(t << 3) + j] = __float2half(w);
    }
  } else {                           // biasUV + y sentinel row
    if (tid < 128) biasUV[tid] = (tid < 64) ? bc1[tid] : 0.f;
    else if (tid < 192) ysent[tid - 128] = __float2half(0.f);
  }
}

// ---------------- MFMA node linear: Y[n,NOUT] = X[n,K] @ packB (+bias) (*dis) --
// wave = 16 rows; A: lane(m16,quad) holds X[row=m16][k=32kc+quad*8+j]
// C/D: lane holds rows quad*4+j, col m16+16nb (verified r3).
template <int K, int NOUT, bool F32IN>
__global__ __launch_bounds__(256) void k_lin_mfma(
    const void* __restrict__ Xv, const __half* __restrict__ packB,
    const float* __restrict__ bias, const float* __restrict__ dis,
    __half* __restrict__ Y, int n) {
  int wid = blockIdx.x * 4 + (threadIdx.x >> 6);
  int rowbase = wid * 16;
  if (rowbase >= n) return;
  int L = threadIdx.x & 63;
  int m16 = L & 15, quad = L >> 4;
  constexpr int KC = K / 32;
  constexpr int NB = NOUT / 16;

  half8 Bf[KC * NB];
  const half8* packv = (const half8*)packB;
#pragma unroll
  for (int f = 0; f < KC * NB; ++f) Bf[f] = packv[f * 64 + L];

  int r = min(rowbase + m16, n - 1);
  half8 Af[KC];
  if (F32IN) {
    const float* xr = (const float*)Xv + (long)r * K;
#pragma unroll
    for (int kc = 0; kc < KC; ++kc) {
      const float4* xp = (const float4*)(xr + kc * 32 + quad * 8);
      float4 a = xp[0], b = xp[1];
      half8 v = {(_Float16)a.x, (_Float16)a.y, (_Float16)a.z, (_Float16)a.w,
                 (_Float16)b.x, (_Float16)b.y, (_Float16)b.z, (_Float16)b.w};
      Af[kc] = v;
    }
  } else {
    const half8* xr = (const half8*)((const __half*)Xv + (long)r * K);
#pragma unroll
    for (int kc = 0; kc < KC; ++kc) Af[kc] = xr[kc * 4 + quad];
  }

  f32x4 acc[NB];
#pragma unroll
  for (int nb = 0; nb < NB; ++nb) acc[nb] = {0.f, 0.f, 0.f, 0.f};
#pragma unroll
  for (int kc = 0; kc < KC; ++kc)
#pragma unroll
    for (int nb = 0; nb < NB; ++nb)
      acc[nb] = __builtin_amdgcn_mfma_f32_16x16x32_f16(Af[kc], Bf[kc * NB + nb],
                                                       acc[nb], 0, 0, 0);

  float dv[4];
#pragma unroll
  for (int j = 0; j < 4; ++j) {
    int ro = rowbase + quad * 4 + j;
    dv[j] = (dis && ro < n) ? dis[ro] : 1.f;
  }
#pragma unroll
  for (int nb = 0; nb < NB; ++nb) {
    int col = m16 + 16 * nb;
    float bv = bias ? bias[col] : 0.f;
#pragma unroll
    for (int j = 0; j < 4; ++j) {
      int ro = rowbase + quad * 4 + j;
      if (ro < n) {
        float v = (acc[nb][j] + bv) * dv[j];
        Y[(long)ro * NOUT + col] = __float2half(v);
      }
    }
  }
}

// ---------------- CSR aggregation: A = dd * (Yh[node] + sum Yh[s]) + b --------
// Yh rows pre-scaled by dis[s]; row n is a zero sentinel for tail slots.
__global__ __launch_bounds__(256) void k_agg_csr(
    const __half* __restrict__ Yh, const float* __restrict__ dis,
    const int* __restrict__ rowoff, const int* __restrict__ csr_src,
    const float* __restrict__ b, __half* __restrict__ A, int n, int E, int relu) {
  int node = blockIdx.x * 4 + (threadIdx.x >> 6);
  if (node >= n) return;
  int L = threadIdx.x & 63;
  int sub = L >> 4;
  int cq = L & 15;
  const half4* Y4 = (const half4*)Yh;
  float dd = dis[node];
  int i0 = rowoff[node];
  int end = (node == n - 1) ? E : rowoff[node + 1];

  float z[4][4] = {{0.f}};
  if (sub == 0) {
    half4 hv = Y4[(long)node * 16 + cq];
#pragma unroll
    for (int j = 0; j < 4; ++j) z[0][j] = (float)hv[j];
  }

  int last = end - 1;
  for (int base = i0; base < end; base += 16) {
    int sidx[4];
#pragma unroll
    for (int slot = 0; slot < 4; ++slot) {
      int idx = base + slot * 4 + sub;
      int sl = csr_src[min(idx, last)];
      sidx[slot] = (idx < end) ? sl : n;
    }
#pragma unroll
    for (int slot = 0; slot < 4; ++slot) {
      half4 hv = Y4[(long)sidx[slot] * 16 + cq];
#pragma unroll
      for (int j = 0; j < 4; ++j) z[slot][j] += (float)hv[j];
    }
  }

  float a[4];
#pragma unroll
  for (int j = 0; j < 4; ++j) {
    a[j] = (z[0][j] + z[1][j]) + (z[2][j] + z[3][j]);
    a[j] += __shfl_xor(a[j], 16, 64);
    a[j] += __shfl_xor(a[j], 32, 64);
  }
  if (sub == 0) {
    float4 bb = ((const float4*)b)[cq];
    float v0 = fmaf(a[0], dd, bb.x), v1 = fmaf(a[1], dd, bb.y);
    float v2 = fmaf(a[2], dd, bb.z), v3 = fmaf(a[3], dd, bb.w);
    if (relu) {
      v0 = fmaxf(v0, 0.f); v1 = fmaxf(v1, 0.f);
      v2 = fmaxf(v2, 0.f); v3 = fmaxf(v3, 0.f);
    }
    half4 o = {(_Float16)v0, (_Float16)v1, (_Float16)v2, (_Float16)v3};
    ((half4*)A)[(long)node * 16 + cq] = o;
  }
}

// ---------------- edge MLP: out_e = relu(U[src]+V[dst]) @ Wc2 + bc2 ----------
__global__ __launch_bounds__(256) void k_edge_mlp(
    const __half* __restrict__ UV, const int* __restrict__ src,
    const int* __restrict__ dst, const float* __restrict__ Wc2,
    const float* __restrict__ bc2, float* __restrict__ out, int E, int nwaves) {
  int wid = blockIdx.x * 4 + (threadIdx.x >> 6);
  int L = threadIdx.x & 63;
  int sub = L >> 4;
  int cq = L & 15;

  float w0[4], w1[4];
#pragma unroll
  for (int j = 0; j < 4; ++j) {
    int c = cq * 4 + j;
    w0[j] = Wc2[2 * c];
    w1[j] = Wc2[2 * c + 1];
  }
  float ob0 = bc2[0], ob1 = bc2[1];

  const half4* UV4 = (const half4*)UV;
  int last = E - 1;

  for (long base = (long)wid * 32; base < E; base += (long)nwaves * 32) {
    int se[8], de[8];
#pragma unroll
    for (int slot = 0; slot < 8; ++slot) {
      int e = (int)base + slot * 4 + sub;
      int ec = min(e, last);
      se[slot] = src[ec];
      de[slot] = dst[ec];
    }
    half4 uu[8], vv[8];
#pragma unroll
    for (int slot = 0; slot < 8; ++slot) {
      uu[slot] = UV4[(long)se[slot] * 32 + cq];
      vv[slot] = UV4[(long)de[slot] * 32 + 16 + cq];
    }
#pragma unroll
    for (int slot = 0; slot < 8; ++slot) {
      float o0 = 0.f, o1 = 0.f;
#pragma unroll
      for (int j = 0; j < 4; ++j) {
        float v = fmaxf((float)uu[slot][j] + (float)vv[slot][j], 0.f);
        o0 = fmaf(v, w0[j], o0);
        o1 = fmaf(v, w1[j], o1);
      }
      o0 += __shfl_xor(o0, 1, 64);
      o1 += __shfl_xor(o1, 1, 64);
      o0 += __shfl_xor(o0, 2, 64);
      o1 += __shfl_xor(o1, 2, 64);
      o0 += __shfl_xor(o0, 4, 64);
      o1 += __shfl_xor(o1, 4, 64);
      o0 += __shfl_xor(o0, 8, 64);
      o1 += __shfl_xor(o1, 8, 64);
      int e = (int)base + slot * 4 + sub;
      if (cq == 0 && e < E) {
        float2 o = {o0 + ob0, o1 + ob1};
        *(float2*)(out + 2 * (long)e) = o;
      }
    }
  }
}

// ---------------- launch ----------------
extern "C" void kernel_launch(void* const* d_in, const int* in_sizes, int n_in,
                              void* d_out, int out_size, void* d_ws, size_t ws_size,
                              hipStream_t stream) {
  const float* x   = (const float*)d_in[0];
  const int*   ei  = (const int*)d_in[1];
  const float* W1  = (const float*)d_in[2];
  const float* b1  = (const float*)d_in[3];
  const float* W2  = (const float*)d_in[4];
  const float* b2  = (const float*)d_in[5];
  const float* Wc1 = (const float*)d_in[6];
  const float* bc1 = (const float*)d_in[7];
  const float* Wc2 = (const float*)d_in[8];
  const float* bc2 = (const float*)d_in[9];

  const int N = in_sizes[0] / 128;
  const int E = in_sizes[1] / 2;
  const int* src = ei;
  const int* dst = ei + E;

  // workspace layout
  float* dis     = (float*)d_ws;                   // N f32
  __half* y      = (__half*)(dis + N);             // (N+1)*64 f16 (sentinel row N)
  __half* h      = y + (long)(N + 1) * HID;        // N*64 f16
  __half* UV     = h + (long)N * HID;              // N*128 f16
  __half* packW1 = UV + (long)N * 128;             // 8192 f16
  __half* packW2 = packW1 + 8192;                  // 4096 f16
  __half* packUV = packW2 + 4096;                  // 8192 f16
  float* biasUV  = (float*)(packUV + 8192);        // 128 f32
  int* degi      = (int*)(biasUV + 128);           // N
  int* scanout   = degi + N;                       // N
  int* rowoff    = scanout + N;                    // N
  int* blocksums = rowoff + N;                     // 128
  int* csr_src   = blocksums + 128;                // E
  int* rank      = (int*)y;  // E ints (6.4MB) < y bytes; no overlap with row N

  const int B = 256;
  int gN  = (N + B - 1) / B;
  int gE  = (E + B - 1) / B;
  int nb  = (N + 1023) / 1024;
  int gLin = (N + 63) / 64;   // 4 waves/block, 16 rows/wave

  // ---- CSR build + packing ----
  hipMemsetAsync(degi, 0, (size_t)N * sizeof(int), stream);
  k_pack_all<<<11, B, 0, stream>>>(W1, W2, Wc1, bc1, packW1, packW2, packUV,
                                   biasUV, y + (long)N * HID);
  k_count_rank<<<gE, B, 0, stream>>>(dst, degi, rank, E);
  k_scan1<<<nb, B, 0, stream>>>(degi, scanout, blocksums, dis, N);
  k_scan2<<<1, 128, 0, stream>>>(blocksums, nb);
  k_scan3<<<gN, B, 0, stream>>>(scanout, blocksums, rowoff, N);
  k_scatter_det<<<gE, B, 0, stream>>>(src, dst, rowoff, rank, csr_src, E);

  int gAgg = (N + 3) / 4;

  // ---- layer 1: y = (x@W1)*dis ; h = relu(dd*(y_self+sum y) + b1) ----
  k_lin_mfma<128, 64, true><<<gLin, B, 0, stream>>>(x, packW1, nullptr, dis, y, N);
  k_agg_csr<<<gAgg, B, 0, stream>>>(y, dis, rowoff, csr_src, b1, h, N, E, 1);

  // ---- layer 2 ----
  k_lin_mfma<64, 64, false><<<gLin, B, 0, stream>>>(h, packW2, nullptr, dis, y, N);
  k_agg_csr<<<gAgg, B, 0, stream>>>(y, dis, rowoff, csr_src, b2, h, N, E, 0);

  // ---- classifier: UV = [h@Wc1a + bc1 | h@Wc1b] ; edge MLP ----
  k_lin_mfma<64, 128, false><<<gLin, B, 0, stream>>>(h, packUV, biasUV, nullptr, UV, N);
  int cblocks = 2048;
  int nwaves = cblocks * 4;
  k_edge_mlp<<<cblocks, B, 0, stream>>>(UV, src, dst, Wc2, bc2,
                                        (float*)d_out, E, nwaves);
}

// Round 10
// 343.009 us; speedup vs baseline: 1.5962x; 1.1311x over previous
//
#include <hip/hip_runtime.h>
#include <hip/hip_fp16.h>

#define HID 64
#define BKT_SHIFT 10
#define BKT_NODES 1024
#define PCHUNKS 512

typedef _Float16 half8 __attribute__((ext_vector_type(8)));
typedef _Float16 half4 __attribute__((ext_vector_type(4)));
typedef float f32x4 __attribute__((ext_vector_type(4)));

// ---------------- pass A: per-(bucket, block) histogram ----------------
__global__ __launch_bounds__(256) void k_bkt_count(const int* __restrict__ dst,
                                                   int* __restrict__ G, int E,
                                                   int nbkt, int chunk) {
  __shared__ int hist[128];
  int p = blockIdx.x, tid = threadIdx.x;
  for (int i = tid; i < nbkt; i += 256) hist[i] = 0;
  __syncthreads();
  int s = p * chunk, e = min(s + chunk, E);
  for (int i = s + tid; i < e; i += 256) atomicAdd(&hist[dst[i] >> BKT_SHIFT], 1);
  __syncthreads();
  for (int b = tid; b < nbkt; b += 256) G[b * PCHUNKS + p] = hist[b];
}

// ---------------- generic exclusive scan (3-kernel), 1024 elems/block ---------
__global__ void k_scan1(const int* __restrict__ in, int* __restrict__ scanout,
                        int* __restrict__ blocksums, int n) {
  __shared__ int sdata[256];
  int tid = threadIdx.x;
  int base = blockIdx.x * 1024 + tid * 4;
  int v0 = 0, v1 = 0, v2 = 0, v3 = 0;
  if (base + 0 < n) v0 = in[base + 0];
  if (base + 1 < n) v1 = in[base + 1];
  if (base + 2 < n) v2 = in[base + 2];
  if (base + 3 < n) v3 = in[base + 3];
  int tsum = v0 + v1 + v2 + v3;
  sdata[tid] = tsum;
  __syncthreads();
  for (int off = 1; off < 256; off <<= 1) {
    int t = (tid >= off) ? sdata[tid - off] : 0;
    __syncthreads();
    sdata[tid] += t;
    __syncthreads();
  }
  int excl = sdata[tid] - tsum;
  if (base + 0 < n) scanout[base + 0] = excl;
  if (base + 1 < n) scanout[base + 1] = excl + v0;
  if (base + 2 < n) scanout[base + 2] = excl + v0 + v1;
  if (base + 3 < n) scanout[base + 3] = excl + v0 + v1 + v2;
  if (tid == 255) blocksums[blockIdx.x] = sdata[255];
}

__global__ void k_scan2(int* blocksums, int nb) {
  __shared__ int s[128];
  int tid = threadIdx.x;
  int v = (tid < nb) ? blocksums[tid] : 0;
  s[tid] = v;
  __syncthreads();
  for (int off = 1; off < 128; off <<= 1) {
    int t = (tid >= off) ? s[tid - off] : 0;
    __syncthreads();
    s[tid] += t;
    __syncthreads();
  }
  if (tid < nb) blocksums[tid] = s[tid] - v;
}

__global__ void k_scan3(const int* __restrict__ scanout,
                        const int* __restrict__ blocksums, int* __restrict__ outp,
                        int n) {
  int i = blockIdx.x * blockDim.x + threadIdx.x;
  if (i < n) outp[i] = scanout[i] + blocksums[i >> 10];
}

// ---------------- pass C: partition edges into bucket-ordered arrays ----------
__global__ __launch_bounds__(256) void k_bkt_scatter(
    const int* __restrict__ src, const int* __restrict__ dst,
    const int* __restrict__ Gscan, int* __restrict__ psrc,
    unsigned short* __restrict__ pdst, int E, int nbkt, int chunk) {
  __shared__ int gbase[128];
  __shared__ int rcnt[128];
  int p = blockIdx.x, tid = threadIdx.x;
  for (int b = tid; b < nbkt; b += 256) {
    gbase[b] = Gscan[b * PCHUNKS + p];
    rcnt[b] = 0;
  }
  __syncthreads();
  int s = p * chunk, e = min(s + chunk, E);
  for (int i = s + tid; i < e; i += 256) {
    int d = dst[i];
    int b = d >> BKT_SHIFT;
    int r = atomicAdd(&rcnt[b], 1);
    int pos = gbase[b] + r;
    psrc[pos] = src[i];
    pdst[pos] = (unsigned short)(d & (BKT_NODES - 1));
  }
}

// ---------------- pass D: per-bucket CSR finalize (rowoff, dis, csr_src) ------
__global__ __launch_bounds__(1024) void k_bkt_final(
    const int* __restrict__ Gscan, const int* __restrict__ psrc,
    const unsigned short* __restrict__ pdst, int* __restrict__ rowoff,
    float* __restrict__ dis, int* __restrict__ csr_src, int E, int nbkt, int N) {
  __shared__ int cnt[BKT_NODES];
  __shared__ int lo[BKT_NODES];
  int b = blockIdx.x, tid = threadIdx.x;
  int s = Gscan[b * PCHUNKS];
  int eend = (b + 1 < nbkt) ? Gscan[(b + 1) * PCHUNKS] : E;
  cnt[tid] = 0;
  __syncthreads();
  for (int i = s + tid; i < eend; i += 1024) atomicAdd(&cnt[pdst[i]], 1);
  __syncthreads();
  int v = cnt[tid];
  lo[tid] = v;
  __syncthreads();
  for (int off = 1; off < 1024; off <<= 1) {
    int t = (tid >= off) ? lo[tid - off] : 0;
    __syncthreads();
    lo[tid] += t;
    __syncthreads();
  }
  int excl = lo[tid] - v;
  int node = b * BKT_NODES + tid;
  if (node < N) {
    rowoff[node] = s + excl;
    dis[node] = rsqrtf((float)v + 1.0f);
  }
  __syncthreads();
  lo[tid] = excl;
  cnt[tid] = 0;
  __syncthreads();
  for (int i = s + tid; i < eend; i += 1024) {
    int ln = pdst[i];
    int r = atomicAdd(&cnt[ln], 1);
    csr_src[s + lo[ln] + r] = psrc[i];
  }
}

// ---------------- fused packing: W1, W2, UV(Wc1) frags + biasUV + y sentinel ---
__global__ void k_pack_all(const float* __restrict__ W1, const float* __restrict__ W2,
                           const float* __restrict__ Wc1, const float* __restrict__ bc1,
                           __half* __restrict__ packW1, __half* __restrict__ packW2,
                           __half* __restrict__ packUV, float* __restrict__ biasUV,
                           __half* __restrict__ ysent) {
  int b = blockIdx.x, tid = threadIdx.x;
  if (b < 4) {
    int t = b * 256 + tid;
    int f = t >> 6, L = t & 63;
    int kc = f >> 2, nb = f & 3;
    int k = 32 * kc + ((L >> 4) << 3);
    int n = (L & 15) + 16 * nb;
    for (int j = 0; j < 8; ++j)
      packW1[(t << 3) + j] = __float2half(W1[(k + j) * 64 + n]);
  } else if (b < 6) {
    int t = (b - 4) * 256 + tid;
    int f = t >> 6, L = t & 63;
    int kc = f >> 2, nb = f & 3;
    int k = 32 * kc + ((L >> 4) << 3);
    int n = (L & 15) + 16 * nb;
    for (int j = 0; j < 8; ++j)
      packW2[(t << 3) + j] = __float2half(W2[(k + j) * 64 + n]);
  } else if (b < 10) {
    int t = (b - 6) * 256 + tid;
    int f = t >> 6, L = t & 63;
    int kc = f >> 3, nb = f & 7;
    int k = 32 * kc + ((L >> 4) << 3);
    int n = (L & 15) + 16 * nb;
    for (int j = 0; j < 8; ++j) {
      float w = (n < 64) ? Wc1[(k + j) * 64 + n] : Wc1[(64 + k + j) * 64 + (n - 64)];
      packUV[(t << 3) + j] = __float2half(w);
    }
  } else {
    if (tid < 128) biasUV[tid] = (tid < 64) ? bc1[tid] : 0.f;
    else if (tid < 192) ysent[tid - 128] = __float2half(0.f);
  }
}

// ---------------- MFMA node linear ----------------
template <int K, int NOUT, bool F32IN>
__global__ __launch_bounds__(256) void k_lin_mfma(
    const void* __restrict__ Xv, const __half* __restrict__ packB,
    const float* __restrict__ bias, const float* __restrict__ dis,
    __half* __restrict__ Y, int n) {
  int wid = blockIdx.x * 4 + (threadIdx.x >> 6);
  int rowbase = wid * 16;
  if (rowbase >= n) return;
  int L = threadIdx.x & 63;
  int m16 = L & 15, quad = L >> 4;
  constexpr int KC = K / 32;
  constexpr int NB = NOUT / 16;

  half8 Bf[KC * NB];
  const half8* packv = (const half8*)packB;
#pragma unroll
  for (int f = 0; f < KC * NB; ++f) Bf[f] = packv[f * 64 + L];

  int r = min(rowbase + m16, n - 1);
  half8 Af[KC];
  if (F32IN) {
    const float* xr = (const float*)Xv + (long)r * K;
#pragma unroll
    for (int kc = 0; kc < KC; ++kc) {
      const float4* xp = (const float4*)(xr + kc * 32 + quad * 8);
      float4 a = xp[0], b = xp[1];
      half8 v = {(_Float16)a.x, (_Float16)a.y, (_Float16)a.z, (_Float16)a.w,
                 (_Float16)b.x, (_Float16)b.y, (_Float16)b.z, (_Float16)b.w};
      Af[kc] = v;
    }
  } else {
    const half8* xr = (const half8*)((const __half*)Xv + (long)r * K);
#pragma unroll
    for (int kc = 0; kc < KC; ++kc) Af[kc] = xr[kc * 4 + quad];
  }

  f32x4 acc[NB];
#pragma unroll
  for (int nb = 0; nb < NB; ++nb) acc[nb] = {0.f, 0.f, 0.f, 0.f};
#pragma unroll
  for (int kc = 0; kc < KC; ++kc)
#pragma unroll
    for (int nb = 0; nb < NB; ++nb)
      acc[nb] = __builtin_amdgcn_mfma_f32_16x16x32_f16(Af[kc], Bf[kc * NB + nb],
                                                       acc[nb], 0, 0, 0);

  float dv[4];
#pragma unroll
  for (int j = 0; j < 4; ++j) {
    int ro = rowbase + quad * 4 + j;
    dv[j] = (dis && ro < n) ? dis[ro] : 1.f;
  }
#pragma unroll
  for (int nb = 0; nb < NB; ++nb) {
    int col = m16 + 16 * nb;
    float bv = bias ? bias[col] : 0.f;
#pragma unroll
    for (int j = 0; j < 4; ++j) {
      int ro = rowbase + quad * 4 + j;
      if (ro < n) {
        float v = (acc[nb][j] + bv) * dv[j];
        Y[(long)ro * NOUT + col] = __float2half(v);
      }
    }
  }
}

// ---------------- CSR aggregation: A = dd * (Yh[node] + sum Yh[s]) + b --------
__global__ __launch_bounds__(256) void k_agg_csr(
    const __half* __restrict__ Yh, const float* __restrict__ dis,
    const int* __restrict__ rowoff, const int* __restrict__ csr_src,
    const float* __restrict__ b, __half* __restrict__ A, int n, int E, int relu) {
  int node = blockIdx.x * 4 + (threadIdx.x >> 6);
  if (node >= n) return;
  int L = threadIdx.x & 63;
  int sub = L >> 4;
  int cq = L & 15;
  const half4* Y4 = (const half4*)Yh;
  float dd = dis[node];
  int i0 = rowoff[node];
  int end = (node == n - 1) ? E : rowoff[node + 1];

  float z[4][4] = {{0.f}};
  if (sub == 0) {
    half4 hv = Y4[(long)node * 16 + cq];
#pragma unroll
    for (int j = 0; j < 4; ++j) z[0][j] = (float)hv[j];
  }

  int last = end - 1;
  for (int base = i0; base < end; base += 16) {
    int sidx[4];
#pragma unroll
    for (int slot = 0; slot < 4; ++slot) {
      int idx = base + slot * 4 + sub;
      int sl = csr_src[min(idx, last)];
      sidx[slot] = (idx < end) ? sl : n;
    }
#pragma unroll
    for (int slot = 0; slot < 4; ++slot) {
      half4 hv = Y4[(long)sidx[slot] * 16 + cq];
#pragma unroll
      for (int j = 0; j < 4; ++j) z[slot][j] += (float)hv[j];
    }
  }

  float a[4];
#pragma unroll
  for (int j = 0; j < 4; ++j) {
    a[j] = (z[0][j] + z[1][j]) + (z[2][j] + z[3][j]);
    a[j] += __shfl_xor(a[j], 16, 64);
    a[j] += __shfl_xor(a[j], 32, 64);
  }
  if (sub == 0) {
    float4 bb = ((const float4*)b)[cq];
    float v0 = fmaf(a[0], dd, bb.x), v1 = fmaf(a[1], dd, bb.y);
    float v2 = fmaf(a[2], dd, bb.z), v3 = fmaf(a[3], dd, bb.w);
    if (relu) {
      v0 = fmaxf(v0, 0.f); v1 = fmaxf(v1, 0.f);
      v2 = fmaxf(v2, 0.f); v3 = fmaxf(v3, 0.f);
    }
    half4 o = {(_Float16)v0, (_Float16)v1, (_Float16)v2, (_Float16)v3};
    ((half4*)A)[(long)node * 16 + cq] = o;
  }
}

// ---------------- edge MLP: out_e = relu(U[src]+V[dst]) @ Wc2 + bc2 ----------
__global__ __launch_bounds__(256) void k_edge_mlp(
    const __half* __restrict__ UV, const int* __restrict__ src,
    const int* __restrict__ dst, const float* __restrict__ Wc2,
    const float* __restrict__ bc2, float* __restrict__ out, int E, int nwaves) {
  int wid = blockIdx.x * 4 + (threadIdx.x >> 6);
  int L = threadIdx.x & 63;
  int sub = L >> 4;
  int cq = L & 15;

  float w0[4], w1[4];
#pragma unroll
  for (int j = 0; j < 4; ++j) {
    int c = cq * 4 + j;
    w0[j] = Wc2[2 * c];
    w1[j] = Wc2[2 * c + 1];
  }
  float ob0 = bc2[0], ob1 = bc2[1];

  const half4* UV4 = (const half4*)UV;
  int last = E - 1;

  for (long base = (long)wid * 32; base < E; base += (long)nwaves * 32) {
    int se[8], de[8];
#pragma unroll
    for (int slot = 0; slot < 8; ++slot) {
      int e = (int)base + slot * 4 + sub;
      int ec = min(e, last);
      se[slot] = src[ec];
      de[slot] = dst[ec];
    }
    half4 uu[8], vv[8];
#pragma unroll
    for (int slot = 0; slot < 8; ++slot) {
      uu[slot] = UV4[(long)se[slot] * 32 + cq];
      vv[slot] = UV4[(long)de[slot] * 32 + 16 + cq];
    }
#pragma unroll
    for (int slot = 0; slot < 8; ++slot) {
      float o0 = 0.f, o1 = 0.f;
#pragma unroll
      for (int j = 0; j < 4; ++j) {
        float v = fmaxf((float)uu[slot][j] + (float)vv[slot][j], 0.f);
        o0 = fmaf(v, w0[j], o0);
        o1 = fmaf(v, w1[j], o1);
      }
      o0 += __shfl_xor(o0, 1, 64);
      o1 += __shfl_xor(o1, 1, 64);
      o0 += __shfl_xor(o0, 2, 64);
      o1 += __shfl_xor(o1, 2, 64);
      o0 += __shfl_xor(o0, 4, 64);
      o1 += __shfl_xor(o1, 4, 64);
      o0 += __shfl_xor(o0, 8, 64);
      o1 += __shfl_xor(o1, 8, 64);
      int e = (int)base + slot * 4 + sub;
      if (cq == 0 && e < E) {
        float2 o = {o0 + ob0, o1 + ob1};
        *(float2*)(out + 2 * (long)e) = o;
      }
    }
  }
}

// ---------------- launch ----------------
extern "C" void kernel_launch(void* const* d_in, const int* in_sizes, int n_in,
                              void* d_out, int out_size, void* d_ws, size_t ws_size,
                              hipStream_t stream) {
  const float* x   = (const float*)d_in[0];
  const int*   ei  = (const int*)d_in[1];
  const float* W1  = (const float*)d_in[2];
  const float* b1  = (const float*)d_in[3];
  const float* W2  = (const float*)d_in[4];
  const float* b2  = (const float*)d_in[5];
  const float* Wc1 = (const float*)d_in[6];
  const float* bc1 = (const float*)d_in[7];
  const float* Wc2 = (const float*)d_in[8];
  const float* bc2 = (const float*)d_in[9];

  const int N = in_sizes[0] / 128;
  const int E = in_sizes[1] / 2;
  const int* src = ei;
  const int* dst = ei + E;

  const int nbkt = (N + BKT_NODES - 1) >> BKT_SHIFT;   // 98
  const int gsz = nbkt * PCHUNKS;                       // 50176
  const int chunk = (E + PCHUNKS - 1) / PCHUNKS;        // 3125

  // workspace layout
  float* dis     = (float*)d_ws;                   // N f32
  __half* y      = (__half*)(dis + N);             // (N+1)*64 f16 (sentinel row N)
  __half* h      = y + (long)(N + 1) * HID;        // N*64 f16
  __half* UV     = h + (long)N * HID;              // N*128 f16
  __half* packW1 = UV + (long)N * 128;             // 8192 f16
  __half* packW2 = packW1 + 8192;                  // 4096 f16
  __half* packUV = packW2 + 4096;                  // 8192 f16
  float* biasUV  = (float*)(packUV + 8192);        // 128 f32
  int* rowoff    = (int*)(biasUV + 128);           // N
  int* csr_src   = rowoff + N;                     // E
  int* G         = csr_src + E;                    // gsz
  int* Gs1       = G + gsz;                        // gsz
  int* Gbs       = Gs1 + gsz;                      // 128
  int* Gscan     = Gbs + 128;                      // gsz
  // partitioned edge arrays alias UV (dead until after k_bkt_final)
  int* psrc            = (int*)UV;                 // E ints (6.4MB < 25.6MB)
  unsigned short* pdst = (unsigned short*)(psrc + E);  // E u16

  const int B = 256;
  int nbScan = (gsz + 1023) / 1024;   // 49

  // ---- packing + bucketed CSR build (no global atomics) ----
  k_pack_all<<<11, B, 0, stream>>>(W1, W2, Wc1, bc1, packW1, packW2, packUV,
                                   biasUV, y + (long)N * HID);
  k_bkt_count<<<PCHUNKS, B, 0, stream>>>(dst, G, E, nbkt, chunk);
  k_scan1<<<nbScan, B, 0, stream>>>(G, Gs1, Gbs, gsz);
  k_scan2<<<1, 128, 0, stream>>>(Gbs, nbScan);
  k_scan3<<<(gsz + B - 1) / B, B, 0, stream>>>(Gs1, Gbs, Gscan, gsz);
  k_bkt_scatter<<<PCHUNKS, B, 0, stream>>>(src, dst, Gscan, psrc, pdst, E, nbkt,
                                           chunk);
  k_bkt_final<<<nbkt, 1024, 0, stream>>>(Gscan, psrc, pdst, rowoff, dis, csr_src,
                                         E, nbkt, N);

  int gAgg = (N + 3) / 4;
  int gLin = (N + 63) / 64;

  // ---- layer 1: y = (x@W1)*dis ; h = relu(dd*(y_self+sum y) + b1) ----
  k_lin_mfma<128, 64, true><<<gLin, B, 0, stream>>>(x, packW1, nullptr, dis, y, N);
  k_agg_csr<<<gAgg, B, 0, stream>>>(y, dis, rowoff, csr_src, b1, h, N, E, 1);

  // ---- layer 2 ----
  k_lin_mfma<64, 64, false><<<gLin, B, 0, stream>>>(h, packW2, nullptr, dis, y, N);
  k_agg_csr<<<gAgg, B, 0, stream>>>(y, dis, rowoff, csr_src, b2, h, N, E, 0);

  // ---- classifier: UV = [h@Wc1a + bc1 | h@Wc1b] ; edge MLP ----
  k_lin_mfma<64, 128, false><<<gLin, B, 0, stream>>>(h, packUV, biasUV, nullptr, UV, N);
  int cblocks = 2048;
  int nwaves = cblocks * 4;
  k_edge_mlp<<<cblocks, B, 0, stream>>>(UV, src, dst, Wc2, bc2,
                                        (float*)d_out, E, nwaves);
}